// Round 6
// baseline (199.897 us; speedup 1.0000x reference)
//
#include <hip/hip_runtime.h>
#include <hip/hip_bf16.h>

// Fused span-pair + attention-pooling model for MI355X (gfx950).
// B=8, N=128, H=768, C=5, P = N(N+1)/2 = 8256.

#define B_ 8
#define N_ 128
#define H_ 768
#define C_ 5
#define P_ 8256
#define TP 64
#define NBLK 129     // P_/TP
#define NSTEP 24     // K steps of 32
#define BSLAB 49152  // one W4 k-slice: 4 koct * 768 cols * 16 B

typedef short bf16x8 __attribute__((ext_vector_type(8)));
typedef float f32x4 __attribute__((ext_vector_type(4)));

__device__ __forceinline__ float bf2f(unsigned short u){
  union { unsigned u; float f; } v; v.u = ((unsigned)u) << 16; return v.f;
}
__device__ __forceinline__ unsigned short f2bf(float f){
  union { float f; unsigned u; } v; v.f = f;
  unsigned r = v.u + 0x7FFFu + ((v.u >> 16) & 1u);
  return (unsigned short)(r >> 16);
}
__device__ __forceinline__ float tanh_fast(float x){
  float e = __expf(2.f * x);
  return 1.f - 2.f / (e + 1.f);
}
// async global->LDS 16B copy: global src is per-lane, LDS dest is
// wave-uniform base + lane*16 (HW adds the lane offset).
__device__ __forceinline__ void gload_lds16(const char* g, char* l){
  __builtin_amdgcn_global_load_lds(
      (const __attribute__((address_space(1))) unsigned int*)g,
      (__attribute__((address_space(3))) unsigned int*)l,
      16, 0, 0);
}
// swizzled LDS byte offset for a [rows][768] bf16 panel (coef_gemm staging)
__device__ __forceinline__ int lds_off(int row, int k){
  return row * (H_ * 2) + ((k * 2) ^ ((row & 15) << 4));
}

// ---------------- prep: pack_h + pack_weights + pairs fused ----------------

#define PH_BLKS 3072   // 786432/256
#define PW_BLKS 288    // 73728/256
#define PR_BLKS 33     // ceil(8256/256)

__global__ void prep(const float* __restrict__ h, const float* __restrict__ Wcat,
                     unsigned short* __restrict__ hb,
                     unsigned short* __restrict__ Wsum,
                     unsigned short* __restrict__ Wdif,
                     unsigned short* __restrict__ W4s,
                     int* __restrict__ ii, int* __restrict__ jj){
  const int bid = blockIdx.x;
  if (bid < PH_BLKS){
    int idx = bid * 256 + threadIdx.x;
    hb[idx] = f2bf(h[idx]);
  } else if (bid < PH_BLKS + PW_BLKS){
    int idx = (bid - PH_BLKS) * 256 + threadIdx.x;   // < 96*768
    int o = idx / H_, col = idx % H_;
    bf16x8 vs, vd, v4;
    #pragma unroll
    for (int e = 0; e < 8; e++){
      int hrow = o * 8 + e;
      float w1 = Wcat[hrow * H_ + col];
      float w2 = Wcat[(H_ + hrow) * H_ + col];
      float w3 = Wcat[(2 * H_ + hrow) * H_ + col];
      float w4 = Wcat[(3 * H_ + hrow) * H_ + col];
      vs[e] = (short)f2bf(w1 + w3);
      vd[e] = (short)f2bf(w2 - w3);
      v4[e] = (short)f2bf(w4);
    }
    int pbase = (o * H_ + col) * 8;
    *(bf16x8*)(Wsum + pbase) = vs;
    *(bf16x8*)(Wdif + pbase) = vd;
    *(bf16x8*)(W4s + pbase)  = v4;
  } else {
    int p = (bid - PH_BLKS - PW_BLKS) * 256 + threadIdx.x;
    if (p < P_){
      int i = 0, off = 0;
      while (off + (N_ - i) <= p){ off += (N_ - i); i++; }
      ii[p] = i; jj[p] = i + (p - off);
    }
  }
}

// ---------------- phase 1: Acoef = h@(W1+W3)+bW, Bcoef = h@(W2-W3) ----------------

__global__ __launch_bounds__(512, 4) void coef_gemm(
    const unsigned short* __restrict__ hb,
    const unsigned short* __restrict__ Wsum,
    const unsigned short* __restrict__ Wdif,
    const float* __restrict__ bW,
    float* __restrict__ Acoef, float* __restrict__ Bcoef){
  const int sel = blockIdx.y;                 // 0 -> Acoef, 1 -> Bcoef
  const unsigned short* Wp = sel ? Wdif : Wsum;
  float* out = sel ? Bcoef : Acoef;
  const int growb = blockIdx.x * 16;          // 16 rows of the 1024 flat rows

  __shared__ char As[16 * H_ * 2];            // 24 KiB swizzled bf16 panel

  const int tid = threadIdx.x;
  { // stage 16 hb rows, k-interleaved
    int r = tid >> 5;          // 0..15
    int c = tid & 31;          // 0..31
    const unsigned short* src = hb + (growb + r) * H_;
    #pragma unroll
    for (int kk = 0; kk < 3; kk++){
      int k = kk * 256 + c * 8;
      bf16x8 v = *(const bf16x8*)(src + k);
      *(bf16x8*)(As + lds_off(r, k)) = v;
    }
  }
  __syncthreads();

  const int lane = tid & 63;
  const int wn = tid >> 6;      // 0..7 : 96-col group
  const int hi = lane >> 4;     // 0..3
  const int l15 = lane & 15;
  const int colbase = wn * 96 + l15;

  f32x4 acc[6] = {};

  // register double-buffered B prefetch (stride one k-step = 4*H_ frags)
  const bf16x8* wp = (const bf16x8*)Wp + hi * H_ + colbase;
  bf16x8 bc0 = wp[0], bc1 = wp[16], bc2 = wp[32], bc3 = wp[48], bc4 = wp[64], bc5 = wp[80];
  wp += 4 * H_;
  for (int step = 0; step < 24; ++step){
    bf16x8 bn0 = wp[0], bn1 = wp[16], bn2 = wp[32], bn3 = wp[48], bn4 = wp[64], bn5 = wp[80];
    wp += 4 * H_;   // last iter reads past Wp into adjacent ws region: safe, discarded
    bf16x8 a = *(const bf16x8*)(As + lds_off(l15, step * 32 + hi * 8));
    acc[0] = __builtin_amdgcn_mfma_f32_16x16x32_bf16(a, bc0, acc[0], 0, 0, 0);
    acc[1] = __builtin_amdgcn_mfma_f32_16x16x32_bf16(a, bc1, acc[1], 0, 0, 0);
    acc[2] = __builtin_amdgcn_mfma_f32_16x16x32_bf16(a, bc2, acc[2], 0, 0, 0);
    acc[3] = __builtin_amdgcn_mfma_f32_16x16x32_bf16(a, bc3, acc[3], 0, 0, 0);
    acc[4] = __builtin_amdgcn_mfma_f32_16x16x32_bf16(a, bc4, acc[4], 0, 0, 0);
    acc[5] = __builtin_amdgcn_mfma_f32_16x16x32_bf16(a, bc5, acc[5], 0, 0, 0);
    bc0 = bn0; bc1 = bn1; bc2 = bn2; bc3 = bn3; bc4 = bn4; bc5 = bn5;
  }

  #pragma unroll
  for (int ni = 0; ni < 6; ni++){
    int col = colbase + ni * 16;
    float bw = (sel == 0) ? bW[col] : 0.f;
    #pragma unroll
    for (int r = 0; r < 4; r++){
      int grow = growb + hi * 4 + r;
      out[grow * H_ + col] = acc[ni][r] + bw;
    }
  }
}

// ---------------- phase 2: fused span GEMM + tanh + online softmax-pool ----------------
// 16 waves, each 64 rows x 48 cols. W4 B-operand staged per k-step (48 KB
// k-slice) into double-buffered LDS via global_load_lds (linear layout match);
// each W4 byte crosses L1 once per block instead of once per wave.
// Product panel: k=128 reg-staged double-buffered slabs (loads 3 steps early).
// __syncthreads' vmcnt(0) drain is the completion guarantee for the async
// staging issued one step earlier (m97 pattern).

__global__ __launch_bounds__(1024, 4)
void spans_fused(
    const unsigned short* __restrict__ hb,
    const float* __restrict__ Acoef,
    const float* __restrict__ Bcoef,
    const unsigned short* __restrict__ W4s,
    const float* __restrict__ hhat,
    const int* __restrict__ ii,
    const int* __restrict__ jj,
    float* __restrict__ pm, float* __restrict__ pl, float* __restrict__ pacc){
  __shared__ char Pp[2][TP * 128 * 2];   // 2 x 16 KB product k-slabs (swizzled)
  __shared__ char Bsl[2][BSLAB];         // 2 x 48 KB W4 k-slices (linear)
  __shared__ int iis[TP], jjs[TP];
  __shared__ float sbuf[16][TP];
  __shared__ float wbuf[TP];

  const int bid = blockIdx.x;
  const int b = bid / NBLK;
  const int p0 = (bid % NBLK) * TP;
  const int tid = threadIdx.x;

  if (tid < TP){ iis[tid] = ii[p0 + tid]; jjs[tid] = jj[p0 + tid]; }
  __syncthreads();

  const int lane = tid & 63;
  const int wave = tid >> 6;     // 0..15 : 48-col group
  const int hi = lane >> 4;      // 0..3
  const int l15 = lane & 15;
  const int colbase = wave * 48 + l15;

  // staging identity: thread owns pair-row r_st, k-chunk c_st*8 (within slab)
  const int r_st = tid >> 4;     // 0..63
  const int c_st = tid & 15;     // 0..15
  const unsigned short* hp = hb + (b * N_ + iis[r_st]) * H_;
  const unsigned short* hq = hb + (b * N_ + jjs[r_st]) * H_;
  const int pwoff = r_st * 256 + ((c_st * 16) ^ ((r_st & 15) << 4));
  const char* wbase = (const char*)W4s;
  const int bchunk = wave * 3072;

  // ---- prologue ----
  // product slab 0 loads
  bf16x8 va = *(const bf16x8*)(hp + c_st * 8);
  bf16x8 vb = *(const bf16x8*)(hq + c_st * 8);
  // accumulator init = Acoef[i,col] + Bcoef[j,col]  (MFMA C-in)
  f32x4 acc[4][3];
  #pragma unroll
  for (int mi = 0; mi < 4; mi++){
    #pragma unroll
    for (int r = 0; r < 4; r++){
      int rowl = mi * 16 + hi * 4 + r;
      const float* ap = Acoef + (b * N_ + iis[rowl]) * H_ + colbase;
      const float* bp = Bcoef + (b * N_ + jjs[rowl]) * H_ + colbase;
      #pragma unroll
      for (int ni = 0; ni < 3; ni++)
        acc[mi][ni][r] = ap[ni * 16] + bp[ni * 16];
    }
  }
  { // write product slab 0
    bf16x8 vp;
    #pragma unroll
    for (int e = 0; e < 8; e++)
      vp[e] = (short)f2bf(bf2f((unsigned short)va[e]) * bf2f((unsigned short)vb[e]));
    *(bf16x8*)(Pp[0] + pwoff) = vp;
  }
  // issue B slice 0
  #pragma unroll
  for (int t = 0; t < 3; t++)
    gload_lds16(wbase + bchunk + t * 1024 + lane * 16,
                Bsl[0] + bchunk + t * 1024);

  // ---- main loop: 24 k-steps of 32 ----
  for (int s = 0; s < NSTEP; ++s){
    const int buf = s & 1;
    const int pbuf = (s >> 2) & 1;
    __syncthreads();   // drains vmcnt+lgkm: B slice s + product writes ready

    // issue next B slice (completion enforced by next step's barrier)
    if (s < NSTEP - 1){
      const char* src = wbase + (s + 1) * BSLAB + bchunk;
      #pragma unroll
      for (int t = 0; t < 3; t++)
        gload_lds16(src + t * 1024 + lane * 16,
                    Bsl[buf ^ 1] + bchunk + t * 1024);
    }
    // issue next product-slab loads 3 steps ahead of use
    if ((s & 3) == 0 && s + 4 < NSTEP){
      const int kg = ((s >> 2) + 1) * 128;
      va = *(const bf16x8*)(hp + kg + c_st * 8);
      vb = *(const bf16x8*)(hq + kg + c_st * 8);
    }

    // compute this k-step
    const int klb = (s & 3) * 64 + hi * 16;   // byte offset of k within slab
    const char* pp = Pp[pbuf];
    bf16x8 a0 = *(const bf16x8*)(pp + (     l15) * 256 + (klb ^ (l15 << 4)));
    bf16x8 a1 = *(const bf16x8*)(pp + (16 + l15) * 256 + (klb ^ (l15 << 4)));
    bf16x8 a2 = *(const bf16x8*)(pp + (32 + l15) * 256 + (klb ^ (l15 << 4)));
    bf16x8 a3 = *(const bf16x8*)(pp + (48 + l15) * 256 + (klb ^ (l15 << 4)));
    const char* bb = Bsl[buf] + (hi * H_ + colbase) * 16;
    #pragma unroll
    for (int ni = 0; ni < 3; ni++){
      bf16x8 bf = *(const bf16x8*)(bb + ni * 256);
      acc[0][ni] = __builtin_amdgcn_mfma_f32_16x16x32_bf16(a0, bf, acc[0][ni], 0, 0, 0);
      acc[1][ni] = __builtin_amdgcn_mfma_f32_16x16x32_bf16(a1, bf, acc[1][ni], 0, 0, 0);
      acc[2][ni] = __builtin_amdgcn_mfma_f32_16x16x32_bf16(a2, bf, acc[2][ni], 0, 0, 0);
      acc[3][ni] = __builtin_amdgcn_mfma_f32_16x16x32_bf16(a3, bf, acc[3][ni], 0, 0, 0);
    }

    // convert + write next product slab (read starts after next barrier)
    if ((s & 3) == 3 && s < NSTEP - 1){
      bf16x8 vp;
      #pragma unroll
      for (int e = 0; e < 8; e++)
        vp[e] = (short)f2bf(bf2f((unsigned short)va[e]) * bf2f((unsigned short)vb[e]));
      *(bf16x8*)(Pp[pbuf ^ 1] + pwoff) = vp;
    }
  }

  // epilogue (pure VALU): spans = tanh(acc); score partials vs h_hat
  float sc[4][4];
  #pragma unroll
  for (int mi = 0; mi < 4; mi++)
    #pragma unroll
    for (int r = 0; r < 4; r++) sc[mi][r] = 0.f;

  #pragma unroll
  for (int ni = 0; ni < 3; ni++){
    float hh = hhat[colbase + ni * 16];
    #pragma unroll
    for (int mi = 0; mi < 4; mi++){
      #pragma unroll
      for (int r = 0; r < 4; r++){
        float s = tanh_fast(acc[mi][ni][r]);
        acc[mi][ni][r] = s;            // keep span in-register
        sc[mi][r] += s * hh;
      }
    }
  }
  // reduce score over the 16-lane column group
  #pragma unroll
  for (int mi = 0; mi < 4; mi++)
    #pragma unroll
    for (int r = 0; r < 4; r++){
      float v = sc[mi][r];
      v += __shfl_xor(v, 1); v += __shfl_xor(v, 2);
      v += __shfl_xor(v, 4); v += __shfl_xor(v, 8);
      sc[mi][r] = v;
    }
  if (l15 == 0){
    #pragma unroll
    for (int mi = 0; mi < 4; mi++)
      #pragma unroll
      for (int r = 0; r < 4; r++)
        sbuf[wave][mi * 16 + hi * 4 + r] = sc[mi][r];
  }
  __syncthreads();

  // block-local softmax weights (wave 0)
  if (tid < TP){
    float s = 0.f;
    #pragma unroll
    for (int w = 0; w < 16; w++) s += sbuf[w][tid];
    float m = s;
    #pragma unroll
    for (int off = 1; off < 64; off <<= 1) m = fmaxf(m, __shfl_xor(m, off));
    float w = __expf(s - m);
    float l = w;
    #pragma unroll
    for (int off = 1; off < 64; off <<= 1) l += __shfl_xor(l, off);
    wbuf[tid] = w;
    if (tid == 0){ pm[bid] = m; pl[bid] = l; }
  }
  __syncthreads();

  // weighted span accumulation -> pacc directly
  #pragma unroll
  for (int ni = 0; ni < 3; ni++){
    float wa = 0.f;
    #pragma unroll
    for (int mi = 0; mi < 4; mi++)
      #pragma unroll
      for (int r = 0; r < 4; r++){
        int rowl = mi * 16 + hi * 4 + r;
        wa += wbuf[rowl] * acc[mi][ni][r];
      }
    wa += __shfl_xor(wa, 16);
    wa += __shfl_xor(wa, 32);
    if (lane < 16) pacc[bid * H_ + colbase + ni * 16] = wa;
  }
}

// ---------------- phase 3a: column-parallel flash-merge of block partials ----------------

__global__ void merge1(
    const float* __restrict__ pm, const float* __restrict__ pl,
    const float* __restrict__ pacc, float* __restrict__ htg){
  __shared__ float ebuf[NBLK];
  __shared__ float Msh, invLsh;
  __shared__ float part[128];
  const int b = blockIdx.x;
  const int ch = blockIdx.y;
  const int tid = threadIdx.x;   // 256

  if (tid < 64){
    float m = -3.4e38f;
    for (int t = tid; t < NBLK; t += 64) m = fmaxf(m, pm[b * NBLK + t]);
    #pragma unroll
    for (int off = 1; off < 64; off <<= 1) m = fmaxf(m, __shfl_xor(m, off));
    float l = 0.f;
    for (int t = tid; t < NBLK; t += 64) l += pl[b * NBLK + t] * __expf(pm[b * NBLK + t] - m);
    #pragma unroll
    for (int off = 1; off < 64; off <<= 1) l += __shfl_xor(l, off);
    if (tid == 0){ Msh = m; invLsh = 1.f / l; }
  }
  __syncthreads();
  if (tid < NBLK) ebuf[tid] = __expf(pm[b * NBLK + tid] - Msh);
  __syncthreads();
  const int col = ch * 128 + (tid & 127);
  const int half = tid >> 7;
  float a = 0.f;
  for (int t = half; t < NBLK; t += 2) a += pacc[(b * NBLK + t) * H_ + col] * ebuf[t];
  if (half) part[tid & 127] = a;
  __syncthreads();
  if (!half) htg[b * H_ + col] = (a + part[tid]) * invLsh;
}

// ---------------- phase 3b: logits + log_softmax ----------------

__global__ void merge2(
    const float* __restrict__ htg,
    const float* __restrict__ Wout, const float* __restrict__ bout,
    float* __restrict__ outp){
  const int b = blockIdx.x;
  const int lane = threadIdx.x;  // 64
  float a[C_] = {};
  for (int k = lane; k < H_; k += 64){
    float hv = htg[b * H_ + k];
    #pragma unroll
    for (int c = 0; c < C_; c++) a[c] += hv * Wout[k * C_ + c];
  }
  #pragma unroll
  for (int c = 0; c < C_; c++){
    #pragma unroll
    for (int off = 1; off < 64; off <<= 1) a[c] += __shfl_xor(a[c], off);
  }
  if (lane == 0){
    float lg[C_];
    #pragma unroll
    for (int c = 0; c < C_; c++) lg[c] = a[c] + bout[c];
    float mx = lg[0];
    #pragma unroll
    for (int c = 1; c < C_; c++) mx = fmaxf(mx, lg[c]);
    float s = 0.f;
    #pragma unroll
    for (int c = 0; c < C_; c++) s += __expf(lg[c] - mx);
    float ls = __logf(s) + mx;
    #pragma unroll
    for (int c = 0; c < C_; c++) outp[b * C_ + c] = lg[c] - ls;
  }
}

// ---------------- launch ----------------

extern "C" void kernel_launch(void* const* d_in, const int* in_sizes, int n_in,
                              void* d_out, int out_size, void* d_ws, size_t ws_size,
                              hipStream_t stream){
  const float* h    = (const float*)d_in[0];
  const float* Wcat = (const float*)d_in[1];
  const float* bW   = (const float*)d_in[2];
  const float* hhat = (const float*)d_in[3];
  const float* Wout = (const float*)d_in[4];
  const float* bout = (const float*)d_in[5];
  float* outp = (float*)d_out;

  // workspace carve-up (~14.7 MB total)
  unsigned short* hb   = (unsigned short*)d_ws;        // 786432 bf16
  unsigned short* Wsum = hb + 786432;                  // 589824 bf16 each
  unsigned short* Wdif = Wsum + 589824;
  unsigned short* W4s  = Wdif + 589824;
  float* Acoef = (float*)(W4s + 589824);               // 786432 f32
  float* Bcoef = Acoef + 786432;                       // 786432 f32
  int* iiA = (int*)(Bcoef + 786432);                   // 8256 i32
  int* jjA = iiA + P_;
  float* pm = (float*)(jjA + P_);                      // 1032 f32
  float* pl = pm + (B_ * NBLK);
  float* pacc = pl + (B_ * NBLK);                      // 1032*768 f32
  float* htg  = pacc + (B_ * NBLK * H_);               // 8*768 f32

  prep<<<PH_BLKS + PW_BLKS + PR_BLKS, 256, 0, stream>>>(h, Wcat, hb, Wsum, Wdif, W4s, iiA, jjA);
  coef_gemm<<<dim3(64, 2), 512, 0, stream>>>(hb, Wsum, Wdif, bW, Acoef, Bcoef);
  spans_fused<<<B_ * NBLK, 1024, 0, stream>>>(hb, Acoef, Bcoef, W4s, hhat, iiA, jjA, pm, pl, pacc);
  merge1<<<dim3(B_, 6), 256, 0, stream>>>(pm, pl, pacc, htg);
  merge2<<<B_, 64, 0, stream>>>(htg, Wout, bout, outp);
}

// Round 7
// 188.949 us; speedup vs baseline: 1.0579x; 1.0579x over previous
//
#include <hip/hip_runtime.h>
#include <hip/hip_bf16.h>

// Fused span-pair + attention-pooling model for MI355X (gfx950).
// B=8, N=128, H=768, C=5, P = N(N+1)/2 = 8256.

#define B_ 8
#define N_ 128
#define H_ 768
#define C_ 5
#define P_ 8256
#define TP 96        // pairs per block (8256 = 86*96 exactly)
#define NBLK 86      // blocks per batch
#define NSTEP 24     // K steps of 32
#define SLABK 128    // product slab k-size
#define NSLAB 6

typedef short bf16x8 __attribute__((ext_vector_type(8)));
typedef float f32x4 __attribute__((ext_vector_type(4)));

__device__ __forceinline__ float bf2f(unsigned short u){
  union { unsigned u; float f; } v; v.u = ((unsigned)u) << 16; return v.f;
}
__device__ __forceinline__ unsigned short f2bf(float f){
  union { float f; unsigned u; } v; v.f = f;
  unsigned r = v.u + 0x7FFFu + ((v.u >> 16) & 1u);
  return (unsigned short)(r >> 16);
}
__device__ __forceinline__ float tanh_fast(float x){
  float e = __expf(2.f * x);
  return 1.f - 2.f / (e + 1.f);
}
// bf16 product pack via v_cvt_pk_bf16_f32 (RNE, 1 instr per 2 elems)
__device__ __forceinline__ bf16x8 prodpack(bf16x8 x, bf16x8 y){
  union { bf16x8 v; unsigned u[4]; } o;
  #pragma unroll
  for (int e2 = 0; e2 < 4; e2++){
    float p0 = bf2f((unsigned short)x[e2*2])   * bf2f((unsigned short)y[e2*2]);
    float p1 = bf2f((unsigned short)x[e2*2+1]) * bf2f((unsigned short)y[e2*2+1]);
    unsigned pk;
    asm volatile("v_cvt_pk_bf16_f32 %0, %1, %2" : "=v"(pk) : "v"(p0), "v"(p1));
    o.u[e2] = pk;
  }
  return o.v;
}
// swizzled LDS byte offset for a [rows][768] bf16 panel (coef_gemm staging)
__device__ __forceinline__ int lds_off(int row, int k){
  return row * (H_ * 2) + ((k * 2) ^ ((row & 15) << 4));
}

// ---------------- prep: pack_h + pack_weights + pairs fused ----------------

#define PH_BLKS 3072   // 786432/256
#define PW_BLKS 288    // 73728/256
#define PR_BLKS 33     // ceil(8256/256)

__global__ void prep(const float* __restrict__ h, const float* __restrict__ Wcat,
                     unsigned short* __restrict__ hb,
                     unsigned short* __restrict__ Wsum,
                     unsigned short* __restrict__ Wdif,
                     unsigned short* __restrict__ W4s,
                     int* __restrict__ ii, int* __restrict__ jj){
  const int bid = blockIdx.x;
  if (bid < PH_BLKS){
    int idx = bid * 256 + threadIdx.x;
    hb[idx] = f2bf(h[idx]);
  } else if (bid < PH_BLKS + PW_BLKS){
    int idx = (bid - PH_BLKS) * 256 + threadIdx.x;   // < 96*768
    int o = idx / H_, col = idx % H_;
    bf16x8 vs, vd, v4;
    #pragma unroll
    for (int e = 0; e < 8; e++){
      int hrow = o * 8 + e;
      float w1 = Wcat[hrow * H_ + col];
      float w2 = Wcat[(H_ + hrow) * H_ + col];
      float w3 = Wcat[(2 * H_ + hrow) * H_ + col];
      float w4 = Wcat[(3 * H_ + hrow) * H_ + col];
      vs[e] = (short)f2bf(w1 + w3);
      vd[e] = (short)f2bf(w2 - w3);
      v4[e] = (short)f2bf(w4);
    }
    int pbase = (o * H_ + col) * 8;
    *(bf16x8*)(Wsum + pbase) = vs;
    *(bf16x8*)(Wdif + pbase) = vd;
    *(bf16x8*)(W4s + pbase)  = v4;
  } else {
    int p = (bid - PH_BLKS - PW_BLKS) * 256 + threadIdx.x;
    if (p < P_){
      int i = 0, off = 0;
      while (off + (N_ - i) <= p){ off += (N_ - i); i++; }
      ii[p] = i; jj[p] = i + (p - off);
    }
  }
}

// ---------------- phase 1: Acoef = h@(W1+W3)+bW, Bcoef = h@(W2-W3) ----------------

__global__ __launch_bounds__(512, 4) void coef_gemm(
    const unsigned short* __restrict__ hb,
    const unsigned short* __restrict__ Wsum,
    const unsigned short* __restrict__ Wdif,
    const float* __restrict__ bW,
    float* __restrict__ Acoef, float* __restrict__ Bcoef){
  const int sel = blockIdx.y;                 // 0 -> Acoef, 1 -> Bcoef
  const unsigned short* Wp = sel ? Wdif : Wsum;
  float* out = sel ? Bcoef : Acoef;
  const int growb = blockIdx.x * 16;          // 16 rows of the 1024 flat rows

  __shared__ char As[16 * H_ * 2];            // 24 KiB swizzled bf16 panel

  const int tid = threadIdx.x;
  { // stage 16 hb rows, k-interleaved
    int r = tid >> 5;          // 0..15
    int c = tid & 31;          // 0..31
    const unsigned short* src = hb + (growb + r) * H_;
    #pragma unroll
    for (int kk = 0; kk < 3; kk++){
      int k = kk * 256 + c * 8;
      bf16x8 v = *(const bf16x8*)(src + k);
      *(bf16x8*)(As + lds_off(r, k)) = v;
    }
  }
  __syncthreads();

  const int lane = tid & 63;
  const int wn = tid >> 6;      // 0..7 : 96-col group
  const int hi = lane >> 4;     // 0..3
  const int l15 = lane & 15;
  const int colbase = wn * 96 + l15;

  f32x4 acc[6] = {};

  // register double-buffered B prefetch (stride one k-step = 4*H_ frags)
  const bf16x8* wp = (const bf16x8*)Wp + hi * H_ + colbase;
  bf16x8 bc0 = wp[0], bc1 = wp[16], bc2 = wp[32], bc3 = wp[48], bc4 = wp[64], bc5 = wp[80];
  wp += 4 * H_;
  for (int step = 0; step < 24; ++step){
    bf16x8 bn0 = wp[0], bn1 = wp[16], bn2 = wp[32], bn3 = wp[48], bn4 = wp[64], bn5 = wp[80];
    wp += 4 * H_;   // last iter reads past Wp into adjacent ws region: safe, discarded
    bf16x8 a = *(const bf16x8*)(As + lds_off(l15, step * 32 + hi * 8));
    acc[0] = __builtin_amdgcn_mfma_f32_16x16x32_bf16(a, bc0, acc[0], 0, 0, 0);
    acc[1] = __builtin_amdgcn_mfma_f32_16x16x32_bf16(a, bc1, acc[1], 0, 0, 0);
    acc[2] = __builtin_amdgcn_mfma_f32_16x16x32_bf16(a, bc2, acc[2], 0, 0, 0);
    acc[3] = __builtin_amdgcn_mfma_f32_16x16x32_bf16(a, bc3, acc[3], 0, 0, 0);
    acc[4] = __builtin_amdgcn_mfma_f32_16x16x32_bf16(a, bc4, acc[4], 0, 0, 0);
    acc[5] = __builtin_amdgcn_mfma_f32_16x16x32_bf16(a, bc5, acc[5], 0, 0, 0);
    bc0 = bn0; bc1 = bn1; bc2 = bn2; bc3 = bn3; bc4 = bn4; bc5 = bn5;
  }

  #pragma unroll
  for (int ni = 0; ni < 6; ni++){
    int col = colbase + ni * 16;
    float bw = (sel == 0) ? bW[col] : 0.f;
    #pragma unroll
    for (int r = 0; r < 4; r++){
      int grow = growb + hi * 4 + r;
      out[grow * H_ + col] = acc[ni][r] + bw;
    }
  }
}

// ---------------- phase 2: fused span GEMM + tanh + online softmax-pool ----------------
// 512 threads / 8 waves at 2 waves/SIMD (256-VGPR budget, HK regime).
// Each wave: 96 rows x 96 cols, acc[6][6]. W4 B-fragments in registers with
// 2-slot prefetch (one full k-step lead ~1400cy). Products staged in 6
// double-buffered 24KB k-slabs; next-slab loads issued 4 steps early.

#define STEP_BODY(T, BCUR, BNXT)                                             \
  {                                                                          \
    if ((T) + 1 < NSTEP){                                                    \
      _Pragma("unroll")                                                      \
      for (int ni = 0; ni < 6; ni++)                                         \
        BNXT[ni] = wp[(((T) + 1) * 4 + hi) * H_ + colbase + ni * 16];        \
    }                                                                        \
    const int klb = ((T) & 3) * 64 + hi * 16;                                \
    bf16x8 a[6];                                                             \
    _Pragma("unroll")                                                        \
    for (int mg = 0; mg < 6; mg++)                                           \
      a[mg] = *(const bf16x8*)(pcur + (mg * 16 + l15) * 256 + (klb ^ (l15 << 4))); \
    __builtin_amdgcn_s_setprio(1);                                           \
    _Pragma("unroll")                                                        \
    for (int ni = 0; ni < 6; ni++){                                          \
      _Pragma("unroll")                                                      \
      for (int mg = 0; mg < 6; mg++)                                         \
        acc[mg][ni] = __builtin_amdgcn_mfma_f32_16x16x32_bf16(a[mg], BCUR[ni], acc[mg][ni], 0, 0, 0); \
    }                                                                        \
    __builtin_amdgcn_s_setprio(0);                                           \
  }

__global__ __launch_bounds__(512, 2)
void spans_fused(
    const unsigned short* __restrict__ hb,
    const float* __restrict__ Acoef,
    const float* __restrict__ Bcoef,
    const unsigned short* __restrict__ W4s,
    const float* __restrict__ hhat,
    const int* __restrict__ ii,
    const int* __restrict__ jj,
    float* __restrict__ pm, float* __restrict__ pl, float* __restrict__ pacc){
  __shared__ char Pp[2][TP * 256];     // 2 x 24 KB product k-slabs (swizzled)
  __shared__ int iis[TP], jjs[TP];
  __shared__ float sbuf[8][TP];
  __shared__ float wbuf[TP];
  __shared__ float Msh;

  const int bid = blockIdx.x;
  const int b = bid / NBLK;
  const int p0 = (bid % NBLK) * TP;
  const int tid = threadIdx.x;

  if (tid < TP){ iis[tid] = ii[p0 + tid]; jjs[tid] = jj[p0 + tid]; }
  __syncthreads();

  const int lane = tid & 63;
  const int wave = tid >> 6;     // 0..7 : 96-col group
  const int hi = lane >> 4;      // 0..3
  const int l15 = lane & 15;
  const int colbase = wave * 96 + l15;

  // staging identity: 3 chunks/thread, chunk cid = tid + t*512 -> row cid>>4, c cid&15
  int rch[3], cch[3];
  const unsigned short *hpr[3], *hqr[3];
  #pragma unroll
  for (int t = 0; t < 3; t++){
    int cid = tid + t * 512;
    rch[t] = cid >> 4; cch[t] = cid & 15;
    hpr[t] = hb + (b * N_ + iis[rch[t]]) * H_;
    hqr[t] = hb + (b * N_ + jjs[rch[t]]) * H_;
  }

  // ---- prologue: issue slab-0 product loads
  bf16x8 va[3], vb[3];
  #pragma unroll
  for (int t = 0; t < 3; t++){
    va[t] = *(const bf16x8*)(hpr[t] + cch[t] * 8);
    vb[t] = *(const bf16x8*)(hqr[t] + cch[t] * 8);
  }

  // accumulator init = Acoef[i,col] + Bcoef[j,col]  (MFMA C-in; hides load latency)
  f32x4 acc[6][6];
  #pragma unroll
  for (int mg = 0; mg < 6; mg++){
    #pragma unroll
    for (int r = 0; r < 4; r++){
      int rowl = mg * 16 + hi * 4 + r;
      const float* ap = Acoef + (b * N_ + iis[rowl]) * H_ + colbase;
      const float* bp = Bcoef + (b * N_ + jjs[rowl]) * H_ + colbase;
      #pragma unroll
      for (int ni = 0; ni < 6; ni++)
        acc[mg][ni][r] = ap[ni * 16] + bp[ni * 16];
    }
  }

  // write slab 0
  #pragma unroll
  for (int t = 0; t < 3; t++)
    *(bf16x8*)(Pp[0] + rch[t] * 256 + ((cch[t] * 16) ^ ((rch[t] & 15) << 4))) =
        prodpack(va[t], vb[t]);

  // B prefetch slot A for step 0
  const bf16x8* wp = (const bf16x8*)W4s;
  bf16x8 bA[6], bB[6];
  #pragma unroll
  for (int ni = 0; ni < 6; ni++)
    bA[ni] = wp[hi * H_ + colbase + ni * 16];

  __syncthreads();

  // ---- main loop: 6 slabs x 4 k-steps
  for (int slab = 0; slab < NSLAB; ++slab){
    const char* pcur = Pp[slab & 1];
    // issue next-slab product loads (4 steps ~5.6k cyc to land)
    if (slab + 1 < NSLAB){
      const int kg = (slab + 1) * SLABK;
      #pragma unroll
      for (int t = 0; t < 3; t++){
        va[t] = *(const bf16x8*)(hpr[t] + kg + cch[t] * 8);
        vb[t] = *(const bf16x8*)(hqr[t] + kg + cch[t] * 8);
      }
    }
    const int t0 = slab * 4;
    STEP_BODY(t0,     bA, bB);
    STEP_BODY(t0 + 1, bB, bA);
    STEP_BODY(t0 + 2, bA, bB);
    STEP_BODY(t0 + 3, bB, bA);
    // convert + write next slab into the other buffer
    if (slab + 1 < NSLAB){
      #pragma unroll
      for (int t = 0; t < 3; t++)
        *(bf16x8*)(Pp[(slab & 1) ^ 1] + rch[t] * 256 +
                   ((cch[t] * 16) ^ ((rch[t] & 15) << 4))) = prodpack(va[t], vb[t]);
    }
    __syncthreads();
  }

  // ---- epilogue: spans = tanh(acc); score partials vs h_hat
  float sc[6][4];
  #pragma unroll
  for (int mg = 0; mg < 6; mg++)
    #pragma unroll
    for (int r = 0; r < 4; r++) sc[mg][r] = 0.f;

  #pragma unroll
  for (int ni = 0; ni < 6; ni++){
    float hh = hhat[colbase + ni * 16];
    #pragma unroll
    for (int mg = 0; mg < 6; mg++){
      #pragma unroll
      for (int r = 0; r < 4; r++){
        float s = tanh_fast(acc[mg][ni][r]);
        acc[mg][ni][r] = s;            // keep span in-register
        sc[mg][r] += s * hh;
      }
    }
  }
  // reduce score over the 16-lane column group
  #pragma unroll
  for (int mg = 0; mg < 6; mg++)
    #pragma unroll
    for (int r = 0; r < 4; r++){
      float v = sc[mg][r];
      v += __shfl_xor(v, 1); v += __shfl_xor(v, 2);
      v += __shfl_xor(v, 4); v += __shfl_xor(v, 8);
      sc[mg][r] = v;
    }
  if (l15 == 0){
    #pragma unroll
    for (int mg = 0; mg < 6; mg++)
      #pragma unroll
      for (int r = 0; r < 4; r++)
        sbuf[wave][mg * 16 + hi * 4 + r] = sc[mg][r];
  }
  __syncthreads();

  // per-row total score
  if (tid < TP){
    float s = 0.f;
    #pragma unroll
    for (int w = 0; w < 8; w++) s += sbuf[w][tid];
    wbuf[tid] = s;
  }
  __syncthreads();
  // softmax over 96 rows (wave 0: 64 lanes cover 64 + 32)
  if (tid < 64){
    float a = wbuf[tid];
    float bq = (tid < 32) ? wbuf[64 + tid] : -3.4e38f;
    float m = fmaxf(a, bq);
    #pragma unroll
    for (int off = 1; off < 64; off <<= 1) m = fmaxf(m, __shfl_xor(m, off));
    float l = __expf(a - m) + ((tid < 32) ? __expf(bq - m) : 0.f);
    #pragma unroll
    for (int off = 1; off < 64; off <<= 1) l += __shfl_xor(l, off);
    if (tid == 0){ pm[bid] = m; pl[bid] = l; Msh = m; }
  }
  __syncthreads();
  if (tid < TP) wbuf[tid] = __expf(wbuf[tid] - Msh);
  __syncthreads();

  // weighted span accumulation -> pacc directly
  #pragma unroll
  for (int ni = 0; ni < 6; ni++){
    float wa = 0.f;
    #pragma unroll
    for (int mg = 0; mg < 6; mg++)
      #pragma unroll
      for (int r = 0; r < 4; r++)
        wa += wbuf[mg * 16 + hi * 4 + r] * acc[mg][ni][r];
    wa += __shfl_xor(wa, 16);
    wa += __shfl_xor(wa, 32);
    if (lane < 16) pacc[bid * H_ + colbase + ni * 16] = wa;
  }
}

// ---------------- phase 3a: column-parallel flash-merge of block partials ----------------

__global__ void merge1(
    const float* __restrict__ pm, const float* __restrict__ pl,
    const float* __restrict__ pacc, float* __restrict__ htg){
  __shared__ float ebuf[NBLK];
  __shared__ float Msh, invLsh;
  __shared__ float part[128];
  const int b = blockIdx.x;
  const int ch = blockIdx.y;
  const int tid = threadIdx.x;   // 256

  if (tid < 64){
    float m = -3.4e38f;
    for (int t = tid; t < NBLK; t += 64) m = fmaxf(m, pm[b * NBLK + t]);
    #pragma unroll
    for (int off = 1; off < 64; off <<= 1) m = fmaxf(m, __shfl_xor(m, off));
    float l = 0.f;
    for (int t = tid; t < NBLK; t += 64) l += pl[b * NBLK + t] * __expf(pm[b * NBLK + t] - m);
    #pragma unroll
    for (int off = 1; off < 64; off <<= 1) l += __shfl_xor(l, off);
    if (tid == 0){ Msh = m; invLsh = 1.f / l; }
  }
  __syncthreads();
  if (tid < NBLK) ebuf[tid] = __expf(pm[b * NBLK + tid] - Msh);
  __syncthreads();
  const int col = ch * 128 + (tid & 127);
  const int half = tid >> 7;
  float a = 0.f;
  for (int t = half; t < NBLK; t += 2) a += pacc[(b * NBLK + t) * H_ + col] * ebuf[t];
  if (half) part[tid & 127] = a;
  __syncthreads();
  if (!half) htg[b * H_ + col] = (a + part[tid]) * invLsh;
}

// ---------------- phase 3b: logits + log_softmax ----------------

__global__ void merge2(
    const float* __restrict__ htg,
    const float* __restrict__ Wout, const float* __restrict__ bout,
    float* __restrict__ outp){
  const int b = blockIdx.x;
  const int lane = threadIdx.x;  // 64
  float a[C_] = {};
  for (int k = lane; k < H_; k += 64){
    float hv = htg[b * H_ + k];
    #pragma unroll
    for (int c = 0; c < C_; c++) a[c] += hv * Wout[k * C_ + c];
  }
  #pragma unroll
  for (int c = 0; c < C_; c++){
    #pragma unroll
    for (int off = 1; off < 64; off <<= 1) a[c] += __shfl_xor(a[c], off);
  }
  if (lane == 0){
    float lg[C_];
    #pragma unroll
    for (int c = 0; c < C_; c++) lg[c] = a[c] + bout[c];
    float mx = lg[0];
    #pragma unroll
    for (int c = 1; c < C_; c++) mx = fmaxf(mx, lg[c]);
    float s = 0.f;
    #pragma unroll
    for (int c = 0; c < C_; c++) s += __expf(lg[c] - mx);
    float ls = __logf(s) + mx;
    #pragma unroll
    for (int c = 0; c < C_; c++) outp[b * C_ + c] = lg[c] - ls;
  }
}

// ---------------- launch ----------------

extern "C" void kernel_launch(void* const* d_in, const int* in_sizes, int n_in,
                              void* d_out, int out_size, void* d_ws, size_t ws_size,
                              hipStream_t stream){
  const float* h    = (const float*)d_in[0];
  const float* Wcat = (const float*)d_in[1];
  const float* bW   = (const float*)d_in[2];
  const float* hhat = (const float*)d_in[3];
  const float* Wout = (const float*)d_in[4];
  const float* bout = (const float*)d_in[5];
  float* outp = (float*)d_out;

  // workspace carve-up (~13.6 MB total)
  unsigned short* hb   = (unsigned short*)d_ws;        // 786432 bf16
  unsigned short* Wsum = hb + 786432;                  // 589824 bf16 each
  unsigned short* Wdif = Wsum + 589824;
  unsigned short* W4s  = Wdif + 589824;
  float* Acoef = (float*)(W4s + 589824);               // 786432 f32
  float* Bcoef = Acoef + 786432;                       // 786432 f32
  int* iiA = (int*)(Bcoef + 786432);                   // 8256 i32
  int* jjA = iiA + P_;
  float* pm = (float*)(jjA + P_);                      // 688 f32
  float* pl = pm + (B_ * NBLK);
  float* pacc = pl + (B_ * NBLK);                      // 688*768 f32
  float* htg  = pacc + (B_ * NBLK * H_);               // 8*768 f32

  prep<<<PH_BLKS + PW_BLKS + PR_BLKS, 256, 0, stream>>>(h, Wcat, hb, Wsum, Wdif, W4s, iiA, jjA);
  coef_gemm<<<dim3(64, 2), 512, 0, stream>>>(hb, Wsum, Wdif, bW, Acoef, Bcoef);
  spans_fused<<<B_ * NBLK, 512, 0, stream>>>(hb, Acoef, Bcoef, W4s, hhat, iiA, jjA, pm, pl, pacc);
  merge1<<<dim3(B_, 6), 256, 0, stream>>>(pm, pl, pacc, htg);
  merge2<<<B_, 64, 0, stream>>>(htg, Wout, bout, outp);
}

// Round 8
// 174.783 us; speedup vs baseline: 1.1437x; 1.0810x over previous
//
#include <hip/hip_runtime.h>
#include <hip/hip_bf16.h>

// Fused span-pair + attention-pooling model for MI355X (gfx950).
// B=8, N=128, H=768, C=5, P = N(N+1)/2 = 8256.

#define B_ 8
#define N_ 128
#define H_ 768
#define C_ 5
#define P_ 8256
#define TP 64
#define NBLK 129     // P_/TP
#define NSTEP 24     // K steps of 32

typedef short bf16x8 __attribute__((ext_vector_type(8)));
typedef float f32x4 __attribute__((ext_vector_type(4)));

__device__ __forceinline__ float bf2f(unsigned short u){
  union { unsigned u; float f; } v; v.u = ((unsigned)u) << 16; return v.f;
}
__device__ __forceinline__ unsigned short f2bf(float f){
  union { float f; unsigned u; } v; v.f = f;
  unsigned r = v.u + 0x7FFFu + ((v.u >> 16) & 1u);
  return (unsigned short)(r >> 16);
}
__device__ __forceinline__ float tanh_fast(float x){
  float e = __expf(2.f * x);
  return 1.f - 2.f / (e + 1.f);
}
// bf16 product pack via v_cvt_pk_bf16_f32 (RNE, 1 instr per 2 elems)
__device__ __forceinline__ bf16x8 prodpack(bf16x8 x, bf16x8 y){
  union { bf16x8 v; unsigned u[4]; } o;
  #pragma unroll
  for (int e2 = 0; e2 < 4; e2++){
    float p0 = bf2f((unsigned short)x[e2*2])   * bf2f((unsigned short)y[e2*2]);
    float p1 = bf2f((unsigned short)x[e2*2+1]) * bf2f((unsigned short)y[e2*2+1]);
    unsigned pk;
    asm volatile("v_cvt_pk_bf16_f32 %0, %1, %2" : "=v"(pk) : "v"(p0), "v"(p1));
    o.u[e2] = pk;
  }
  return o.v;
}
// swizzled LDS byte offset for a [rows][768] bf16 panel; row stride 1536B.
// XOR bits 4..7 with row: 16 stride-aligned rows -> 16 distinct 16B slots
// (all 32 banks) for ds_read_b128 columns. Verified conflict-free (R5-R7: 0).
__device__ __forceinline__ int lds_off(int row, int k){
  return row * (H_ * 2) + ((k * 2) ^ ((row & 15) << 4));
}

// ---------------- prep: pack_h + pack_weights + pairs fused ----------------

#define PH_BLKS 3072   // 786432/256
#define PW_BLKS 288    // 73728/256
#define PR_BLKS 33     // ceil(8256/256)

__global__ void prep(const float* __restrict__ h, const float* __restrict__ Wcat,
                     unsigned short* __restrict__ hb,
                     unsigned short* __restrict__ Wsum,
                     unsigned short* __restrict__ Wdif,
                     unsigned short* __restrict__ W4s,
                     int* __restrict__ ii, int* __restrict__ jj){
  const int bid = blockIdx.x;
  if (bid < PH_BLKS){
    int idx = bid * 256 + threadIdx.x;
    hb[idx] = f2bf(h[idx]);
  } else if (bid < PH_BLKS + PW_BLKS){
    int idx = (bid - PH_BLKS) * 256 + threadIdx.x;   // < 96*768
    int o = idx / H_, col = idx % H_;
    bf16x8 vs, vd, v4;
    #pragma unroll
    for (int e = 0; e < 8; e++){
      int hrow = o * 8 + e;
      float w1 = Wcat[hrow * H_ + col];
      float w2 = Wcat[(H_ + hrow) * H_ + col];
      float w3 = Wcat[(2 * H_ + hrow) * H_ + col];
      float w4 = Wcat[(3 * H_ + hrow) * H_ + col];
      vs[e] = (short)f2bf(w1 + w3);
      vd[e] = (short)f2bf(w2 - w3);
      v4[e] = (short)f2bf(w4);
    }
    int pbase = (o * H_ + col) * 8;
    *(bf16x8*)(Wsum + pbase) = vs;
    *(bf16x8*)(Wdif + pbase) = vd;
    *(bf16x8*)(W4s + pbase)  = v4;
  } else {
    int p = (bid - PH_BLKS - PW_BLKS) * 256 + threadIdx.x;
    if (p < P_){
      int i = 0, off = 0;
      while (off + (N_ - i) <= p){ off += (N_ - i); i++; }
      ii[p] = i; jj[p] = i + (p - off);
    }
  }
}

// ---------------- phase 1: Acoef = h@(W1+W3)+bW, Bcoef = h@(W2-W3) ----------------

__global__ __launch_bounds__(512, 4) void coef_gemm(
    const unsigned short* __restrict__ hb,
    const unsigned short* __restrict__ Wsum,
    const unsigned short* __restrict__ Wdif,
    const float* __restrict__ bW,
    float* __restrict__ Acoef, float* __restrict__ Bcoef){
  const int sel = blockIdx.y;                 // 0 -> Acoef, 1 -> Bcoef
  const unsigned short* Wp = sel ? Wdif : Wsum;
  float* out = sel ? Bcoef : Acoef;
  const int growb = blockIdx.x * 16;          // 16 rows of the 1024 flat rows

  __shared__ char As[16 * H_ * 2];            // 24 KiB swizzled bf16 panel

  const int tid = threadIdx.x;
  { // stage 16 hb rows, k-interleaved
    int r = tid >> 5;          // 0..15
    int c = tid & 31;          // 0..31
    const unsigned short* src = hb + (growb + r) * H_;
    #pragma unroll
    for (int kk = 0; kk < 3; kk++){
      int k = kk * 256 + c * 8;
      bf16x8 v = *(const bf16x8*)(src + k);
      *(bf16x8*)(As + lds_off(r, k)) = v;
    }
  }
  __syncthreads();

  const int lane = tid & 63;
  const int wn = tid >> 6;      // 0..7 : 96-col group
  const int hi = lane >> 4;     // 0..3
  const int l15 = lane & 15;
  const int colbase = wn * 96 + l15;

  f32x4 acc[6] = {};

  // register double-buffered B prefetch (stride one k-step = 4*H_ frags)
  const bf16x8* wp = (const bf16x8*)Wp + hi * H_ + colbase;
  bf16x8 bc0 = wp[0], bc1 = wp[16], bc2 = wp[32], bc3 = wp[48], bc4 = wp[64], bc5 = wp[80];
  wp += 4 * H_;
  for (int step = 0; step < 24; ++step){
    bf16x8 bn0 = wp[0], bn1 = wp[16], bn2 = wp[32], bn3 = wp[48], bn4 = wp[64], bn5 = wp[80];
    wp += 4 * H_;   // last iter reads past Wp into adjacent ws region: safe, discarded
    bf16x8 a = *(const bf16x8*)(As + lds_off(l15, step * 32 + hi * 8));
    acc[0] = __builtin_amdgcn_mfma_f32_16x16x32_bf16(a, bc0, acc[0], 0, 0, 0);
    acc[1] = __builtin_amdgcn_mfma_f32_16x16x32_bf16(a, bc1, acc[1], 0, 0, 0);
    acc[2] = __builtin_amdgcn_mfma_f32_16x16x32_bf16(a, bc2, acc[2], 0, 0, 0);
    acc[3] = __builtin_amdgcn_mfma_f32_16x16x32_bf16(a, bc3, acc[3], 0, 0, 0);
    acc[4] = __builtin_amdgcn_mfma_f32_16x16x32_bf16(a, bc4, acc[4], 0, 0, 0);
    acc[5] = __builtin_amdgcn_mfma_f32_16x16x32_bf16(a, bc5, acc[5], 0, 0, 0);
    bc0 = bn0; bc1 = bn1; bc2 = bn2; bc3 = bn3; bc4 = bn4; bc5 = bn5;
  }

  #pragma unroll
  for (int ni = 0; ni < 6; ni++){
    int col = colbase + ni * 16;
    float bw = (sel == 0) ? bW[col] : 0.f;
    #pragma unroll
    for (int r = 0; r < 4; r++){
      int grow = growb + hi * 4 + r;
      out[grow * H_ + col] = acc[ni][r] + bw;
    }
  }
}

// ---------------- phase 2: fused span GEMM + tanh + online softmax-pool ----------------
// 1024 threads / 16 waves, each wave 64 rows x 48 cols (acc[4][3], coef C-in).
// Monolithic 96KB swizzled product panel, no intra-K barriers.
// W4 B-fragments: 3-slot rotating register pipeline, prefetch lead 2 steps
// (~466 cyc >= L2 latency; lead-1 in R4/R5 exposed ~50% stall -> 22% MfmaUtil).

__global__ __launch_bounds__(1024, 4)
void spans_fused(
    const unsigned short* __restrict__ hb,
    const float* __restrict__ Acoef,
    const float* __restrict__ Bcoef,
    const unsigned short* __restrict__ W4s,
    const float* __restrict__ hhat,
    const int* __restrict__ ii,
    const int* __restrict__ jj,
    float* __restrict__ pm, float* __restrict__ pl, float* __restrict__ pacc){
  __shared__ char As[TP * H_ * 2];       // 96 KiB swizzled product panel
  __shared__ int iis[TP], jjs[TP];
  __shared__ float sbuf[16][TP];
  __shared__ float wbuf[TP];

  const int bid = blockIdx.x;
  const int b = bid / NBLK;
  const int p0 = (bid % NBLK) * TP;
  const int tid = threadIdx.x;

  if (tid < TP){ iis[tid] = ii[p0 + tid]; jjs[tid] = jj[p0 + tid]; }
  __syncthreads();

  { // stage products h_i (.) h_j (bf16), k-interleaved: k = kk*128 + c*8
    int r = tid >> 4;      // 0..63 pair row
    int c = tid & 15;      // 0..15
    const unsigned short* hp = hb + (b * N_ + iis[r]) * H_;
    const unsigned short* hq = hb + (b * N_ + jjs[r]) * H_;
    #pragma unroll
    for (int kk = 0; kk < 6; kk++){
      int k = kk * 128 + c * 8;
      bf16x8 va = *(const bf16x8*)(hp + k);
      bf16x8 vb = *(const bf16x8*)(hq + k);
      *(bf16x8*)(As + lds_off(r, k)) = prodpack(va, vb);
    }
  }

  const int lane = tid & 63;
  const int wave = tid >> 6;     // 0..15 : 48-col group
  const int hi = lane >> 4;      // 0..3
  const int l15 = lane & 15;
  const int colbase = wave * 48 + l15;

  // accumulator init = Acoef[i,col] + Bcoef[j,col]  (MFMA C-in; overlaps staging)
  f32x4 acc[4][3];
  #pragma unroll
  for (int mi = 0; mi < 4; mi++){
    #pragma unroll
    for (int r = 0; r < 4; r++){
      int rowl = mi * 16 + hi * 4 + r;
      const float* ap = Acoef + (b * N_ + iis[rowl]) * H_ + colbase;
      const float* bp = Bcoef + (b * N_ + jjs[rowl]) * H_ + colbase;
      #pragma unroll
      for (int ni = 0; ni < 3; ni++)
        acc[mi][ni][r] = ap[ni * 16] + bp[ni * 16];
    }
  }

  // 3-slot B pipeline prologue: load steps 0 and 1
  const bf16x8* wp = (const bf16x8*)W4s + hi * H_ + colbase;
  bf16x8 bs[3][3];
  #pragma unroll
  for (int s = 0; s < 2; s++)
    #pragma unroll
    for (int ni = 0; ni < 3; ni++)
      bs[s][ni] = wp[s * 4 * H_ + ni * 16];

  __syncthreads();

  // ---- main K loop: fully unrolled so bs[t%3] indices are compile-time
  #pragma unroll
  for (int t = 0; t < NSTEP; ++t){
    // issue B loads for step t+2 (lead 2)
    if (t + 2 < NSTEP){
      #pragma unroll
      for (int ni = 0; ni < 3; ni++)
        bs[(t + 2) % 3][ni] = wp[(t + 2) * 4 * H_ + ni * 16];
    }
    const int kb = t * 32 + hi * 8;
    bf16x8 a0 = *(const bf16x8*)(As + lds_off(     l15, kb));
    bf16x8 a1 = *(const bf16x8*)(As + lds_off(16 + l15, kb));
    bf16x8 a2 = *(const bf16x8*)(As + lds_off(32 + l15, kb));
    bf16x8 a3 = *(const bf16x8*)(As + lds_off(48 + l15, kb));
    #pragma unroll
    for (int ni = 0; ni < 3; ni++){
      bf16x8 bfr = bs[t % 3][ni];
      acc[0][ni] = __builtin_amdgcn_mfma_f32_16x16x32_bf16(a0, bfr, acc[0][ni], 0, 0, 0);
      acc[1][ni] = __builtin_amdgcn_mfma_f32_16x16x32_bf16(a1, bfr, acc[1][ni], 0, 0, 0);
      acc[2][ni] = __builtin_amdgcn_mfma_f32_16x16x32_bf16(a2, bfr, acc[2][ni], 0, 0, 0);
      acc[3][ni] = __builtin_amdgcn_mfma_f32_16x16x32_bf16(a3, bfr, acc[3][ni], 0, 0, 0);
    }
  }

  // epilogue (pure VALU): spans = tanh(acc); score partials vs h_hat
  float sc[4][4];
  #pragma unroll
  for (int mi = 0; mi < 4; mi++)
    #pragma unroll
    for (int r = 0; r < 4; r++) sc[mi][r] = 0.f;

  #pragma unroll
  for (int ni = 0; ni < 3; ni++){
    float hh = hhat[colbase + ni * 16];
    #pragma unroll
    for (int mi = 0; mi < 4; mi++){
      #pragma unroll
      for (int r = 0; r < 4; r++){
        float s = tanh_fast(acc[mi][ni][r]);
        acc[mi][ni][r] = s;            // keep span in-register
        sc[mi][r] += s * hh;
      }
    }
  }
  // reduce score over the 16-lane column group
  #pragma unroll
  for (int mi = 0; mi < 4; mi++)
    #pragma unroll
    for (int r = 0; r < 4; r++){
      float v = sc[mi][r];
      v += __shfl_xor(v, 1); v += __shfl_xor(v, 2);
      v += __shfl_xor(v, 4); v += __shfl_xor(v, 8);
      sc[mi][r] = v;
    }
  if (l15 == 0){
    #pragma unroll
    for (int mi = 0; mi < 4; mi++)
      #pragma unroll
      for (int r = 0; r < 4; r++)
        sbuf[wave][mi * 16 + hi * 4 + r] = sc[mi][r];
  }
  __syncthreads();

  // block-local softmax weights (wave 0)
  if (tid < TP){
    float s = 0.f;
    #pragma unroll
    for (int w = 0; w < 16; w++) s += sbuf[w][tid];
    float m = s;
    #pragma unroll
    for (int off = 1; off < 64; off <<= 1) m = fmaxf(m, __shfl_xor(m, off));
    float w = __expf(s - m);
    float l = w;
    #pragma unroll
    for (int off = 1; off < 64; off <<= 1) l += __shfl_xor(l, off);
    wbuf[tid] = w;
    if (tid == 0){ pm[bid] = m; pl[bid] = l; }
  }
  __syncthreads();

  // weighted span accumulation -> pacc directly
  #pragma unroll
  for (int ni = 0; ni < 3; ni++){
    float wa = 0.f;
    #pragma unroll
    for (int mi = 0; mi < 4; mi++)
      #pragma unroll
      for (int r = 0; r < 4; r++){
        int rowl = mi * 16 + hi * 4 + r;
        wa += wbuf[rowl] * acc[mi][ni][r];
      }
    wa += __shfl_xor(wa, 16);
    wa += __shfl_xor(wa, 32);
    if (lane < 16) pacc[bid * H_ + colbase + ni * 16] = wa;
  }
}

// ---------------- phase 3a: column-parallel flash-merge of block partials ----------------

__global__ void merge1(
    const float* __restrict__ pm, const float* __restrict__ pl,
    const float* __restrict__ pacc, float* __restrict__ htg){
  __shared__ float ebuf[NBLK];
  __shared__ float Msh, invLsh;
  __shared__ float part[128];
  const int b = blockIdx.x;
  const int ch = blockIdx.y;
  const int tid = threadIdx.x;   // 256

  if (tid < 64){
    float m = -3.4e38f;
    for (int t = tid; t < NBLK; t += 64) m = fmaxf(m, pm[b * NBLK + t]);
    #pragma unroll
    for (int off = 1; off < 64; off <<= 1) m = fmaxf(m, __shfl_xor(m, off));
    float l = 0.f;
    for (int t = tid; t < NBLK; t += 64) l += pl[b * NBLK + t] * __expf(pm[b * NBLK + t] - m);
    #pragma unroll
    for (int off = 1; off < 64; off <<= 1) l += __shfl_xor(l, off);
    if (tid == 0){ Msh = m; invLsh = 1.f / l; }
  }
  __syncthreads();
  if (tid < NBLK) ebuf[tid] = __expf(pm[b * NBLK + tid] - Msh);
  __syncthreads();
  const int col = ch * 128 + (tid & 127);
  const int half = tid >> 7;
  float a = 0.f;
  for (int t = half; t < NBLK; t += 2) a += pacc[(b * NBLK + t) * H_ + col] * ebuf[t];
  if (half) part[tid & 127] = a;
  __syncthreads();
  if (!half) htg[b * H_ + col] = (a + part[tid]) * invLsh;
}

// ---------------- phase 3b: logits + log_softmax ----------------

__global__ void merge2(
    const float* __restrict__ htg,
    const float* __restrict__ Wout, const float* __restrict__ bout,
    float* __restrict__ outp){
  const int b = blockIdx.x;
  const int lane = threadIdx.x;  // 64
  float a[C_] = {};
  for (int k = lane; k < H_; k += 64){
    float hv = htg[b * H_ + k];
    #pragma unroll
    for (int c = 0; c < C_; c++) a[c] += hv * Wout[k * C_ + c];
  }
  #pragma unroll
  for (int c = 0; c < C_; c++){
    #pragma unroll
    for (int off = 1; off < 64; off <<= 1) a[c] += __shfl_xor(a[c], off);
  }
  if (lane == 0){
    float lg[C_];
    #pragma unroll
    for (int c = 0; c < C_; c++) lg[c] = a[c] + bout[c];
    float mx = lg[0];
    #pragma unroll
    for (int c = 1; c < C_; c++) mx = fmaxf(mx, lg[c]);
    float s = 0.f;
    #pragma unroll
    for (int c = 0; c < C_; c++) s += __expf(lg[c] - mx);
    float ls = __logf(s) + mx;
    #pragma unroll
    for (int c = 0; c < C_; c++) outp[b * C_ + c] = lg[c] - ls;
  }
}

// ---------------- launch ----------------

extern "C" void kernel_launch(void* const* d_in, const int* in_sizes, int n_in,
                              void* d_out, int out_size, void* d_ws, size_t ws_size,
                              hipStream_t stream){
  const float* h    = (const float*)d_in[0];
  const float* Wcat = (const float*)d_in[1];
  const float* bW   = (const float*)d_in[2];
  const float* hhat = (const float*)d_in[3];
  const float* Wout = (const float*)d_in[4];
  const float* bout = (const float*)d_in[5];
  float* outp = (float*)d_out;

  // workspace carve-up (~14.7 MB total)
  unsigned short* hb   = (unsigned short*)d_ws;        // 786432 bf16
  unsigned short* Wsum = hb + 786432;                  // 589824 bf16 each
  unsigned short* Wdif = Wsum + 589824;
  unsigned short* W4s  = Wdif + 589824;
  float* Acoef = (float*)(W4s + 589824);               // 786432 f32
  float* Bcoef = Acoef + 786432;                       // 786432 f32
  int* iiA = (int*)(Bcoef + 786432);                   // 8256 i32
  int* jjA = iiA + P_;
  float* pm = (float*)(jjA + P_);                      // 1032 f32
  float* pl = pm + (B_ * NBLK);
  float* pacc = pl + (B_ * NBLK);                      // 1032*768 f32
  float* htg  = pacc + (B_ * NBLK * H_);               // 8*768 f32

  prep<<<PH_BLKS + PW_BLKS + PR_BLKS, 256, 0, stream>>>(h, Wcat, hb, Wsum, Wdif, W4s, iiA, jjA);
  coef_gemm<<<dim3(64, 2), 512, 0, stream>>>(hb, Wsum, Wdif, bW, Acoef, Bcoef);
  spans_fused<<<B_ * NBLK, 1024, 0, stream>>>(hb, Acoef, Bcoef, W4s, hhat, iiA, jjA, pm, pl, pacc);
  merge1<<<dim3(B_, 6), 256, 0, stream>>>(pm, pl, pacc, htg);
  merge2<<<B_, 64, 0, stream>>>(htg, Wout, bout, outp);
}